// Round 1
// baseline (9077.374 us; speedup 1.0000x reference)
//
#include <hip/hip_runtime.h>
#include <cmath>

// Volume: [B=4, C=1, D=128, H=128, W=128] fp32
#define NB 4
#define ND 128
#define NH 128
#define NW 128
#define NVOX (NB * ND * NH * NW)   // 8388608

#define THREADS 256
#define BLOCKS ((NVOX + THREADS - 1) / THREADS)

// ---------------------------------------------------------------------------
// block reduction helper: returns full-block sum on thread 0
// ---------------------------------------------------------------------------
__device__ __forceinline__ float block_reduce(float v, float* sbuf) {
    // wave64 reduce
    for (int off = 32; off > 0; off >>= 1) v += __shfl_down(v, off, 64);
    int lane = threadIdx.x & 63;
    int wid  = threadIdx.x >> 6;
    if (lane == 0) sbuf[wid] = v;
    __syncthreads();
    float r = 0.f;
    if (wid == 0) {
        int nw = blockDim.x >> 6;
        r = (lane < nw) ? sbuf[lane] : 0.f;
        for (int off = 8; off > 0; off >>= 1) r += __shfl_down(r, off, 64);
    }
    __syncthreads();   // so sbuf can be reused by a subsequent call
    return r;
}

// ---------------------------------------------------------------------------
// sigmoid + dice partial sums: yp = sigmoid(logits); accumulate
// red[0]+=sum(yp), red[1]+=sum(yt), red[2]+=sum(yt*yp)
// ---------------------------------------------------------------------------
__global__ void sigmoid_reduce_kernel(const float* __restrict__ logits,
                                      const float* __restrict__ yt,
                                      float* __restrict__ yp,
                                      float* __restrict__ red) {
    __shared__ float sbuf[THREADS / 64];
    int idx = blockIdx.x * blockDim.x + threadIdx.x;
    float p = 0.f, t = 0.f;
    if (idx < NVOX) {
        p = 1.f / (1.f + expf(-logits[idx]));
        yp[idx] = p;
        t = yt[idx];
    }
    float sp  = block_reduce(p, sbuf);
    float st  = block_reduce(t, sbuf);
    float stp = block_reduce(t * p, sbuf);
    if (threadIdx.x == 0) {
        atomicAdd(&red[0], sp);
        atomicAdd(&red[1], st);
        atomicAdd(&red[2], stp);
    }
}

// ---------------------------------------------------------------------------
// soft_erode: 7-point plus-stencil min (OOB neighbors ignored == +inf pad)
// ---------------------------------------------------------------------------
__global__ void erode_kernel(const float* __restrict__ in, float* __restrict__ out) {
    int idx = blockIdx.x * blockDim.x + threadIdx.x;
    if (idx >= NVOX) return;
    int w = idx & (NW - 1);
    int h = (idx >> 7) & (NH - 1);
    int d = (idx >> 14) & (ND - 1);
    float v = in[idx];
    if (w > 0)      v = fminf(v, in[idx - 1]);
    if (w < NW - 1) v = fminf(v, in[idx + 1]);
    if (h > 0)      v = fminf(v, in[idx - NW]);
    if (h < NH - 1) v = fminf(v, in[idx + NW]);
    if (d > 0)      v = fminf(v, in[idx - NW * NH]);
    if (d < ND - 1) v = fminf(v, in[idx + NW * NH]);
    out[idx] = v;
}

// ---------------------------------------------------------------------------
// fused: m = dilate3x3x3(t)  (27-pt max, OOB ignored == -inf pad)
//   delta = relu(img - m)
//   init : skel = delta
//   else : skel += relu(delta - skel*delta)
// ---------------------------------------------------------------------------
__global__ void dilate_update_kernel(const float* __restrict__ t,
                                     const float* __restrict__ img,
                                     float* __restrict__ skel,
                                     int init) {
    int idx = blockIdx.x * blockDim.x + threadIdx.x;
    if (idx >= NVOX) return;
    int w = idx & (NW - 1);
    int h = (idx >> 7) & (NH - 1);
    int d = (idx >> 14) & (ND - 1);

    float m = -INFINITY;
#pragma unroll
    for (int dz = -1; dz <= 1; ++dz) {
        int dd = d + dz;
        if (dd < 0 || dd >= ND) continue;
#pragma unroll
        for (int dy = -1; dy <= 1; ++dy) {
            int hh = h + dy;
            if (hh < 0 || hh >= NH) continue;
            int base = idx + dz * (NW * NH) + dy * NW;
            float r = t[base];
            if (w > 0)      r = fmaxf(r, t[base - 1]);
            if (w < NW - 1) r = fmaxf(r, t[base + 1]);
            m = fmaxf(m, r);
        }
    }
    float delta = fmaxf(img[idx] - m, 0.f);
    if (init) {
        skel[idx] = delta;
    } else {
        float s = skel[idx];
        skel[idx] = s + fmaxf(delta - s * delta, 0.f);
    }
}

// ---------------------------------------------------------------------------
// reduce: red[off] += sum(a), red[off+1] += sum(a*b)
// ---------------------------------------------------------------------------
__global__ void reduce2_kernel(const float* __restrict__ a,
                               const float* __restrict__ b,
                               float* __restrict__ red, int off) {
    __shared__ float sbuf[THREADS / 64];
    int idx = blockIdx.x * blockDim.x + threadIdx.x;
    float va = 0.f, vab = 0.f;
    if (idx < NVOX) {
        va  = a[idx];
        vab = va * b[idx];
    }
    float sa  = block_reduce(va, sbuf);
    float sab = block_reduce(vab, sbuf);
    if (threadIdx.x == 0) {
        atomicAdd(&red[off], sa);
        atomicAdd(&red[off + 1], sab);
    }
}

// ---------------------------------------------------------------------------
// finalize: red = [sum_yp, sum_yt, sum_yt_yp, sum_skP, sum_skP_yt, sum_skT, sum_skT_yp]
// ---------------------------------------------------------------------------
__global__ void finalize_kernel(const float* __restrict__ red, float* __restrict__ out) {
    const float smooth = 1.0f;
    const float alpha = 0.3f;
    float dice = 1.f - (2.f * red[2] + smooth) / (red[1] + red[0] + smooth);
    float tprec = (red[4] + smooth) / (red[3] + smooth);
    float tsens = (red[6] + smooth) / (red[5] + smooth);
    float cl = 1.f - 2.f * (tprec * tsens) / (tprec + tsens);
    out[0] = (1.f - alpha) * dice + alpha * cl;
}

// ---------------------------------------------------------------------------
// host launcher
// ---------------------------------------------------------------------------
extern "C" void kernel_launch(void* const* d_in, const int* in_sizes, int n_in,
                              void* d_out, int out_size, void* d_ws, size_t ws_size,
                              hipStream_t stream) {
    const float* y_pred = (const float*)d_in[0];
    const float* y_true = (const float*)d_in[1];
    float* out = (float*)d_out;

    char* ws = (char*)d_ws;
    float* red = (float*)ws;                      // 7 floats used
    const size_t bufElems = (size_t)NVOX;
    float* yp   = (float*)(ws + 256);
    float* imgA = yp   + bufElems;
    float* imgB = imgA + bufElems;
    float* T    = imgB + bufElems;
    float* S    = T    + bufElems;

    hipMemsetAsync(red, 0, 64, stream);

    sigmoid_reduce_kernel<<<BLOCKS, THREADS, 0, stream>>>(y_pred, y_true, yp, red);

    auto run_skel = [&](const float* x) {
        // init: skel = relu(x - dilate(erode(x)))
        erode_kernel<<<BLOCKS, THREADS, 0, stream>>>(x, T);
        dilate_update_kernel<<<BLOCKS, THREADS, 0, stream>>>(T, x, S, 1);
        const float* cur = x;
        float* ping = imgA;
        float* pong = imgB;
        for (int i = 0; i < 16; ++i) {
            erode_kernel<<<BLOCKS, THREADS, 0, stream>>>(cur, ping);       // img = erode(img)
            erode_kernel<<<BLOCKS, THREADS, 0, stream>>>(ping, T);         // erode(img)
            dilate_update_kernel<<<BLOCKS, THREADS, 0, stream>>>(T, ping, S, 0); // open + skel update
            cur = ping;
            float* tmp = ping; ping = pong; pong = tmp;
        }
    };

    // skeleton of prediction
    run_skel(yp);
    reduce2_kernel<<<BLOCKS, THREADS, 0, stream>>>(S, y_true, red, 3);

    // skeleton of ground truth
    run_skel(y_true);
    reduce2_kernel<<<BLOCKS, THREADS, 0, stream>>>(S, yp, red, 5);

    finalize_kernel<<<1, 1, 0, stream>>>(red, out);
}

// Round 2
// 6154.079 us; speedup vs baseline: 1.4750x; 1.4750x over previous
//
#include <hip/hip_runtime.h>
#include <cmath>

// Volume: [B=4, C=1, D=128, H=128, W=128] fp32
#define NB 4
#define ND 128
#define NH 128
#define NW 128
#define NVOX (NB * ND * NH * NW)   // 8388608
#define NVOL_VOX (ND * NH * NW)    // 2097152

#define THREADS 256

// Fused skeleton-iteration tile geometry
#define TS 16                 // output tile edge
#define HALO 3
#define LT (TS + 2*HALO)      // 22 : img tile extent (halo 3)
#define LE (TS + 4)           // 20 : e1 extent (halo 2)
#define LF (TS + 2)           // 18 : e2 extent (halo 1)

// ---------------------------------------------------------------------------
// block reduction helper: returns full-block sum on thread 0
// ---------------------------------------------------------------------------
__device__ __forceinline__ float block_reduce(float v, float* sbuf) {
    for (int off = 32; off > 0; off >>= 1) v += __shfl_down(v, off, 64);
    int lane = threadIdx.x & 63;
    int wid  = threadIdx.x >> 6;
    if (lane == 0) sbuf[wid] = v;
    __syncthreads();
    float r = 0.f;
    if (wid == 0) {
        int nw = blockDim.x >> 6;
        r = (lane < nw) ? sbuf[lane] : 0.f;
        for (int off = 8; off > 0; off >>= 1) r += __shfl_down(r, off, 64);
    }
    __syncthreads();
    return r;
}

// ---------------------------------------------------------------------------
// sigmoid + dice partial sums (float4, grid-stride, few blocks => few atomics)
// red[0]+=sum(yp), red[1]+=sum(yt), red[2]+=sum(yt*yp)
// ---------------------------------------------------------------------------
#define SIG_BLOCKS 2048
__global__ void sigmoid_reduce_kernel(const float4* __restrict__ logits,
                                      const float4* __restrict__ yt,
                                      float4* __restrict__ yp,
                                      float* __restrict__ red) {
    __shared__ float sbuf[THREADS / 64];
    const int n4 = NVOX / 4;
    float sp = 0.f, st = 0.f, stp = 0.f;
    for (int i = blockIdx.x * blockDim.x + threadIdx.x; i < n4;
         i += gridDim.x * blockDim.x) {
        float4 l = logits[i];
        float4 t = yt[i];
        float4 p;
        p.x = 1.f / (1.f + expf(-l.x));
        p.y = 1.f / (1.f + expf(-l.y));
        p.z = 1.f / (1.f + expf(-l.z));
        p.w = 1.f / (1.f + expf(-l.w));
        yp[i] = p;
        sp  += p.x + p.y + p.z + p.w;
        st  += t.x + t.y + t.z + t.w;
        stp += t.x * p.x + t.y * p.y + t.z * p.z + t.w * p.w;
    }
    float a = block_reduce(sp, sbuf);
    float b = block_reduce(st, sbuf);
    float c = block_reduce(stp, sbuf);
    if (threadIdx.x == 0) {
        atomicAdd(&red[0], a);
        atomicAdd(&red[1], b);
        atomicAdd(&red[2], c);
    }
}

// ---------------------------------------------------------------------------
// Fused skeleton step.
// MODE=0 (init):  skel = relu(src - dilate(erode(src)))
// MODE=1 (iter):  e1 = erode(src); imgOut = e1;
//                 delta = relu(e1 - dilate(erode(e1)));
//                 skel += relu(delta - skel*delta)
// erode = 7-pt plus-min (OOB ignored == +inf pad)
// dilate = 27-pt max   (OOB ignored == -inf pad)
// ---------------------------------------------------------------------------
template <int MODE>
__global__ __launch_bounds__(256, 2)
void skel_step_kernel(const float* __restrict__ src,
                      float* __restrict__ imgOut,
                      float* __restrict__ skel) {
    __shared__ float A[LT * LT * LT];   // img tile (halo 3); reused for e2 (stride LF)
    __shared__ float B[LE * LE * LE];   // e1 (halo 2)

    const int t   = blockIdx.x;          // 0..511 tile within volume
    const int vol = blockIdx.y;          // 0..3
    const int tx = (t & 7) * TS;
    const int ty = ((t >> 3) & 7) * TS;
    const int tz = (t >> 6) * TS;
    const size_t volBase = (size_t)vol * NVOL_VOX;
    const int tid = threadIdx.x;

    // ---- load img tile with halo 3; +INF outside the global volume ----
    for (int l = tid; l < LT * LT * LT; l += THREADS) {
        int lz = l / (LT * LT);
        int r  = l - lz * (LT * LT);
        int ly = r / LT;
        int lx = r - ly * LT;
        int gz = tz + lz - HALO, gy = ty + ly - HALO, gx = tx + lx - HALO;
        float v = INFINITY;
        if ((unsigned)gz < ND && (unsigned)gy < NH && (unsigned)gx < NW)
            v = src[volBase + ((size_t)gz * NH + gy) * NW + gx];
        A[l] = v;
    }
    __syncthreads();

    // ---- e1 = erode(img) over halo-2 extent (20^3), from A ----
    for (int l = tid; l < LE * LE * LE; l += THREADS) {
        int ez = l / (LE * LE);
        int r  = l - ez * (LE * LE);
        int ey = r / LE;
        int ex = r - ey * LE;
        int c = ((ez + 1) * LT + (ey + 1)) * LT + (ex + 1);
        float v = A[c];
        v = fminf(v, A[c - 1]);       v = fminf(v, A[c + 1]);
        v = fminf(v, A[c - LT]);      v = fminf(v, A[c + LT]);
        v = fminf(v, A[c - LT * LT]); v = fminf(v, A[c + LT * LT]);
        B[l] = v;
        if (MODE == 1) {
            int cz = ez - 2, cy = ey - 2, cx = ex - 2;
            if ((unsigned)cz < TS && (unsigned)cy < TS && (unsigned)cx < TS)
                imgOut[volBase + ((size_t)(tz + cz) * NH + (ty + cy)) * NW + (tx + cx)] = v;
        }
    }
    __syncthreads();

    if (MODE == 1) {
        // ---- e2 = erode(e1) over halo-1 extent (18^3), from B into A (stride LF) ----
        for (int l = tid; l < LF * LF * LF; l += THREADS) {
            int fz = l / (LF * LF);
            int r  = l - fz * (LF * LF);
            int fy = r / LF;
            int fx = r - fy * LF;
            int c = ((fz + 1) * LE + (fy + 1)) * LE + (fx + 1);
            float v = B[c];
            v = fminf(v, B[c - 1]);       v = fminf(v, B[c + 1]);
            v = fminf(v, B[c - LE]);      v = fminf(v, B[c + LE]);
            v = fminf(v, B[c - LE * LE]); v = fminf(v, B[c + LE * LE]);
            A[l] = v;
        }
        __syncthreads();
    }

    // ---- dilate + delta + skel update over the 16^3 center ----
    for (int l = tid; l < TS * TS * TS; l += THREADS) {
        int cz = l / (TS * TS);
        int r  = l - cz * (TS * TS);
        int cy = r / TS;
        int cx = r - cy * TS;
        int gz = tz + cz, gy = ty + cy, gx = tx + cx;

        float dil = -INFINITY;
#pragma unroll
        for (int dz = -1; dz <= 1; ++dz) {
            if ((unsigned)(gz + dz) >= ND) continue;
#pragma unroll
            for (int dy = -1; dy <= 1; ++dy) {
                if ((unsigned)(gy + dy) >= NH) continue;
#pragma unroll
                for (int dx = -1; dx <= 1; ++dx) {
                    if ((unsigned)(gx + dx) >= NW) continue;
                    float e;
                    if (MODE == 1)
                        e = A[((cz + dz + 1) * LF + (cy + dy + 1)) * LF + (cx + dx + 1)];
                    else
                        e = B[((cz + dz + 2) * LE + (cy + dy + 2)) * LE + (cx + dx + 2)];
                    dil = fmaxf(dil, e);
                }
            }
        }

        size_t g = volBase + ((size_t)gz * NH + gy) * NW + gx;
        float refv;
        if (MODE == 1)
            refv = B[((cz + 2) * LE + (cy + 2)) * LE + (cx + 2)];   // e1 center
        else
            refv = A[((cz + 3) * LT + (cy + 3)) * LT + (cx + 3)];   // img center
        float delta = fmaxf(refv - dil, 0.f);
        if (MODE == 1) {
            float s = skel[g];
            skel[g] = s + fmaxf(delta - s * delta, 0.f);
        } else {
            skel[g] = delta;
        }
    }
}

// ---------------------------------------------------------------------------
// reduce: red[off] += sum(a), red[off+1] += sum(a*b)   (float4, grid-stride)
// ---------------------------------------------------------------------------
#define RED_BLOCKS 1024
__global__ void reduce2_kernel(const float4* __restrict__ a,
                               const float4* __restrict__ b,
                               float* __restrict__ red, int off) {
    __shared__ float sbuf[THREADS / 64];
    const int n4 = NVOX / 4;
    float sa = 0.f, sab = 0.f;
    for (int i = blockIdx.x * blockDim.x + threadIdx.x; i < n4;
         i += gridDim.x * blockDim.x) {
        float4 va = a[i];
        float4 vb = b[i];
        sa  += va.x + va.y + va.z + va.w;
        sab += va.x * vb.x + va.y * vb.y + va.z * vb.z + va.w * vb.w;
    }
    float ra  = block_reduce(sa, sbuf);
    float rab = block_reduce(sab, sbuf);
    if (threadIdx.x == 0) {
        atomicAdd(&red[off], ra);
        atomicAdd(&red[off + 1], rab);
    }
}

// ---------------------------------------------------------------------------
// finalize: red = [sum_yp, sum_yt, sum_yt_yp, sum_skP, sum_skP_yt, sum_skT, sum_skT_yp]
// ---------------------------------------------------------------------------
__global__ void finalize_kernel(const float* __restrict__ red, float* __restrict__ out) {
    const float smooth = 1.0f;
    const float alpha = 0.3f;
    float dice = 1.f - (2.f * red[2] + smooth) / (red[1] + red[0] + smooth);
    float tprec = (red[4] + smooth) / (red[3] + smooth);
    float tsens = (red[6] + smooth) / (red[5] + smooth);
    float cl = 1.f - 2.f * (tprec * tsens) / (tprec + tsens);
    out[0] = (1.f - alpha) * dice + alpha * cl;
}

// ---------------------------------------------------------------------------
// host launcher
// ---------------------------------------------------------------------------
extern "C" void kernel_launch(void* const* d_in, const int* in_sizes, int n_in,
                              void* d_out, int out_size, void* d_ws, size_t ws_size,
                              hipStream_t stream) {
    const float* y_pred = (const float*)d_in[0];
    const float* y_true = (const float*)d_in[1];
    float* out = (float*)d_out;

    char* ws = (char*)d_ws;
    float* red = (float*)ws;                  // 7 floats used
    const size_t bufElems = (size_t)NVOX;
    float* yp   = (float*)(ws + 256);
    float* imgA = yp   + bufElems;
    float* imgB = imgA + bufElems;
    float* S    = imgB + bufElems;

    hipMemsetAsync(red, 0, 64, stream);

    sigmoid_reduce_kernel<<<SIG_BLOCKS, THREADS, 0, stream>>>(
        (const float4*)y_pred, (const float4*)y_true, (float4*)yp, red);

    dim3 sgrid(512, NB);

    auto run_skel = [&](const float* x) {
        // init: skel = relu(x - dilate(erode(x)))
        skel_step_kernel<0><<<sgrid, THREADS, 0, stream>>>(x, nullptr, S);
        const float* cur = x;
        float* ping = imgA;
        float* pong = imgB;
        for (int i = 0; i < 16; ++i) {
            skel_step_kernel<1><<<sgrid, THREADS, 0, stream>>>(cur, ping, S);
            cur = ping;
            float* tmp = ping; ping = pong; pong = tmp;
        }
    };

    run_skel(yp);
    reduce2_kernel<<<RED_BLOCKS, THREADS, 0, stream>>>(
        (const float4*)S, (const float4*)y_true, red, 3);

    run_skel(y_true);
    reduce2_kernel<<<RED_BLOCKS, THREADS, 0, stream>>>(
        (const float4*)S, (const float4*)yp, red, 5);

    finalize_kernel<<<1, 1, 0, stream>>>(red, out);
}

// Round 3
// 2511.062 us; speedup vs baseline: 3.6150x; 2.4508x over previous
//
#include <hip/hip_runtime.h>
#include <cmath>

// Volume: [B=4, C=1, D=128, H=128, W=128] fp32
#define NB 4
#define ND 128
#define NH 128
#define NW 128
#define NVOL_VOX (ND * NH * NW)    // 2097152 per volume
#define NVOX (NB * NVOL_VOX)       // 8388608 (4 volumes)

#define THREADS 256

// z-march tile geometry: 32 (x) x 16 (y) outputs, rolling slices in z
#define TX 32
#define TY 16
#define SXW (TX + 6)   // 38  src slice width  (halo 3)
#define SXH (TY + 6)   // 22  src slice height
#define E1W (TX + 4)   // 36  e1 slice (halo 2)
#define E1H (TY + 4)   // 20
#define E2W (TX + 2)   // 34  e2 slice (halo 1)
#define E2H (TY + 2)   // 18
#define MW  TX         // 32  xy-max-reduced dilate slice
#define MH  TY         // 16

// ---------------------------------------------------------------------------
__device__ __forceinline__ float block_reduce(float v, float* sbuf) {
    for (int off = 32; off > 0; off >>= 1) v += __shfl_down(v, off, 64);
    int lane = threadIdx.x & 63;
    int wid  = threadIdx.x >> 6;
    if (lane == 0) sbuf[wid] = v;
    __syncthreads();
    float r = 0.f;
    if (wid == 0) {
        r = (lane < (int)(blockDim.x >> 6)) ? sbuf[lane] : 0.f;
        for (int off = 8; off > 0; off >>= 1) r += __shfl_down(r, off, 64);
    }
    __syncthreads();
    return r;
}

// ---------------------------------------------------------------------------
// sigmoid + dice partial sums (float4, grid-stride)
// red[0]+=sum(yp), red[1]+=sum(yt), red[2]+=sum(yt*yp)
// ---------------------------------------------------------------------------
#define SIG_BLOCKS 2048
__global__ void sigmoid_reduce_kernel(const float4* __restrict__ logits,
                                      const float4* __restrict__ yt,
                                      float4* __restrict__ yp,
                                      float* __restrict__ red) {
    __shared__ float sbuf[THREADS / 64];
    const int n4 = NVOX / 4;
    float sp = 0.f, st = 0.f, stp = 0.f;
    for (int i = blockIdx.x * blockDim.x + threadIdx.x; i < n4;
         i += gridDim.x * blockDim.x) {
        float4 l = logits[i];
        float4 t = yt[i];
        float4 p;
        p.x = 1.f / (1.f + expf(-l.x));
        p.y = 1.f / (1.f + expf(-l.y));
        p.z = 1.f / (1.f + expf(-l.z));
        p.w = 1.f / (1.f + expf(-l.w));
        yp[i] = p;
        sp  += p.x + p.y + p.z + p.w;
        st  += t.x + t.y + t.z + t.w;
        stp += t.x * p.x + t.y * p.y + t.z * p.z + t.w * p.w;
    }
    float a = block_reduce(sp, sbuf);
    float b = block_reduce(st, sbuf);
    float c = block_reduce(stp, sbuf);
    if (threadIdx.x == 0) {
        atomicAdd(&red[0], a);
        atomicAdd(&red[1], b);
        atomicAdd(&red[2], c);
    }
}

// ---------------------------------------------------------------------------
// Fused z-march skeleton step.
// MODE=0 (init): skel = relu(src - dilate(erode(src)))
// MODE=1 (iter): e1 = erode(src); img = e1;
//                delta = relu(e1 - dilate(erode(e1)));
//                skel += relu(delta - skel*delta)
// RED=1: accumulate sum(skel_new) and sum(skel_new * other) into red.
// Grid: (NW/TX, NH/TY, zchunks * nvols). Two input streams (A: vols 0-3,
// B: vols 4-7) when srcB != nullptr.
// ---------------------------------------------------------------------------
template <int MODE, int RED>
__global__ __launch_bounds__(256, 4)
void skel_step_kernel(const float* __restrict__ srcA, const float* __restrict__ srcB,
                      float* __restrict__ imgOut, float* __restrict__ skel,
                      int zchunks,
                      const float* __restrict__ othA, const float* __restrict__ othB,
                      float* __restrict__ red, int offBase) {
    __shared__ float sSrc[4][SXH * SXW];   // rolling src slices (4 slots)
    __shared__ float sE1[3][E1H * E1W];    // rolling e1 slices
    __shared__ float sMxy[3][MH * MW];     // rolling xy-max(dilate) slices
    __shared__ float sE2[E2H * E2W];       // scratch e2 slice (also reduce sbuf)

    const int zlen  = ND / zchunks;
    const int v     = blockIdx.z / zchunks;
    const int chunk = blockIdx.z - v * zchunks;
    const int z0    = chunk * zlen;
    const int tx0   = blockIdx.x * TX;
    const int ty0   = blockIdx.y * TY;
    const int tid   = threadIdx.x;

    const float* src = srcB ? (v < 4 ? srcA + (size_t)v * NVOL_VOX
                                     : srcB + (size_t)(v - 4) * NVOL_VOX)
                            : srcA + (size_t)v * NVOL_VOX;
    float* img = imgOut ? imgOut + (size_t)v * NVOL_VOX : nullptr;
    float* skl = skel + (size_t)v * NVOL_VOX;
    const float* oth = nullptr;
    int off = offBase;
    if (RED) {
        oth = othB ? (v < 4 ? othA + (size_t)v * NVOL_VOX
                            : othB + (size_t)(v - 4) * NVOL_VOX)
                   : othA + (size_t)v * NVOL_VOX;
        if (othB && v >= 4) off = offBase + 2;
    }

    float accS = 0.f, accSO = 0.f;

    // ---- stage: load src slice z (halo 3 in xy; OOB anywhere -> +INF) ----
    auto L = [&](int z) {
        float* dst = sSrc[(z + 512) & 3];
        if ((unsigned)z >= ND) {
            for (int l = tid; l < SXH * SXW; l += THREADS) dst[l] = INFINITY;
        } else {
            const float* sp = src + (size_t)z * (NH * NW);
            for (int l = tid; l < SXH * SXW; l += THREADS) {
                int ly = l / SXW, lx = l - ly * SXW;
                int gy = ty0 + ly - 3, gx = tx0 + lx - 3;
                float vv = INFINITY;
                if ((unsigned)gy < NH && (unsigned)gx < NW) vv = sp[gy * NW + gx];
                dst[l] = vv;
            }
        }
    };

    // ---- stage: e1(z) = 7-pt min erode of src; also write img center ----
    auto E1 = [&](int z) {
        float* dst = sE1[(z + 513) % 3];
        if ((unsigned)z >= ND) {
            for (int l = tid; l < E1H * E1W; l += THREADS) dst[l] = INFINITY;
            return;
        }
        const float* s0 = sSrc[(z - 1 + 512) & 3];
        const float* s1 = sSrc[(z + 512) & 3];
        const float* s2 = sSrc[(z + 1 + 512) & 3];
        const bool wr = (MODE == 1) && z >= z0 && z < z0 + zlen;
        for (int l = tid; l < E1H * E1W; l += THREADS) {
            int ey = l / E1W, ex = l - ey * E1W;
            int c = (ey + 1) * SXW + (ex + 1);
            float vv = s1[c];
            vv = fminf(vv, s1[c - 1]);   vv = fminf(vv, s1[c + 1]);
            vv = fminf(vv, s1[c - SXW]); vv = fminf(vv, s1[c + SXW]);
            vv = fminf(vv, s0[c]);       vv = fminf(vv, s2[c]);
            dst[l] = vv;
            if (wr) {
                int cy = ey - 2, cx = ex - 2;
                if ((unsigned)cy < TY && (unsigned)cx < TX)
                    img[((size_t)z * NH + (ty0 + cy)) * NW + (tx0 + cx)] = vv;
            }
        }
    };

    // ---- stage: mxy(z) = 3x3 xy-max of e2(z); e2 = erode(e1) (MODE1) or e1 ----
    auto MXY = [&](int z) {
        float* dst = sMxy[(z + 513) % 3];
        if ((unsigned)z >= ND) {
            for (int l = tid; l < MH * MW; l += THREADS) dst[l] = -INFINITY;
            return;
        }
        const float* e0 = sE1[(z - 1 + 513) % 3];
        const float* e1 = sE1[(z + 513) % 3];
        const float* e2 = sE1[(z + 1 + 513) % 3];
        if (MODE == 1) {
            for (int l = tid; l < E2H * E2W; l += THREADS) {
                int fy = l / E2W, fx = l - fy * E2W;
                int c = (fy + 1) * E1W + (fx + 1);
                float vv = e1[c];
                vv = fminf(vv, e1[c - 1]);   vv = fminf(vv, e1[c + 1]);
                vv = fminf(vv, e1[c - E1W]); vv = fminf(vv, e1[c + E1W]);
                vv = fminf(vv, e0[c]);       vv = fminf(vv, e2[c]);
                sE2[l] = vv;
            }
        } else {
            for (int l = tid; l < E2H * E2W; l += THREADS) {
                int fy = l / E2W, fx = l - fy * E2W;
                sE2[l] = e1[(fy + 1) * E1W + (fx + 1)];
            }
        }
        __syncthreads();
        for (int l = tid; l < MH * MW; l += THREADS) {
            int my = l / MW, mx = l - my * MW;
            int b = (my + 1) * E2W + (mx + 1);
            float vv = sE2[b];
            vv = fmaxf(vv, sE2[b - 1]);           vv = fmaxf(vv, sE2[b + 1]);
            vv = fmaxf(vv, sE2[b - E2W]);         vv = fmaxf(vv, sE2[b + E2W]);
            vv = fmaxf(vv, sE2[b - E2W - 1]);     vv = fmaxf(vv, sE2[b - E2W + 1]);
            vv = fmaxf(vv, sE2[b + E2W - 1]);     vv = fmaxf(vv, sE2[b + E2W + 1]);
            dst[l] = vv;
        }
    };

    // ---- stage: output slice z ----
    auto OUT = [&](int z) {
        const float* m0 = sMxy[(z - 1 + 513) % 3];
        const float* m1 = sMxy[(z + 513) % 3];
        const float* m2 = sMxy[(z + 1 + 513) % 3];
        const float* refE = sE1[(z + 513) % 3];
        const float* refS = sSrc[(z + 512) & 3];
        for (int l = tid; l < MH * MW; l += THREADS) {
            int my = l / MW, mx = l - my * MW;
            float dil = fmaxf(fmaxf(m0[l], m1[l]), m2[l]);
            float ref = (MODE == 1) ? refE[(my + 2) * E1W + (mx + 2)]
                                    : refS[(my + 3) * SXW + (mx + 3)];
            float delta = fmaxf(ref - dil, 0.f);
            size_t g = ((size_t)z * NH + (ty0 + my)) * NW + (tx0 + mx);
            float snew;
            if (MODE == 1) {
                float s = skl[g];
                snew = s + fmaxf(delta - s * delta, 0.f);
            } else {
                snew = delta;
            }
            skl[g] = snew;
            if (RED) {
                accS  += snew;
                accSO += snew * oth[g];
            }
        }
    };

    // ---- prologue: fill pipeline for this z-chunk ----
    L(z0 - 3); L(z0 - 2); L(z0 - 1); __syncthreads();
    E1(z0 - 2); __syncthreads();
    L(z0);      __syncthreads();
    E1(z0 - 1); __syncthreads();
    L(z0 + 1);  __syncthreads();
    E1(z0);     __syncthreads();
    MXY(z0 - 1); __syncthreads();
    L(z0 + 2);  __syncthreads();
    E1(z0 + 1); __syncthreads();
    MXY(z0);    __syncthreads();

    // ---- steady state ----
    for (int z = z0; z < z0 + zlen; ++z) {
        L(z + 3);   __syncthreads();
        E1(z + 2);  __syncthreads();
        MXY(z + 1); __syncthreads();
        OUT(z);     __syncthreads();
    }

    if (RED) {
        float r1 = block_reduce(accS, sE2);
        float r2 = block_reduce(accSO, sE2);
        if (tid == 0) {
            atomicAdd(&red[off], r1);
            atomicAdd(&red[off + 1], r2);
        }
    }
}

// ---------------------------------------------------------------------------
// finalize: red = [sum_yp, sum_yt, sum_yt_yp, sum_skP, sum_skP_yt, sum_skT, sum_skT_yp]
// ---------------------------------------------------------------------------
__global__ void finalize_kernel(const float* __restrict__ red, float* __restrict__ out) {
    const float smooth = 1.0f;
    const float alpha = 0.3f;
    float dice = 1.f - (2.f * red[2] + smooth) / (red[1] + red[0] + smooth);
    float tprec = (red[4] + smooth) / (red[3] + smooth);
    float tsens = (red[6] + smooth) / (red[5] + smooth);
    float cl = 1.f - 2.f * (tprec * tsens) / (tprec + tsens);
    out[0] = (1.f - alpha) * dice + alpha * cl;
}

// ---------------------------------------------------------------------------
// host launcher
// ---------------------------------------------------------------------------
extern "C" void kernel_launch(void* const* d_in, const int* in_sizes, int n_in,
                              void* d_out, int out_size, void* d_ws, size_t ws_size,
                              hipStream_t stream) {
    const float* y_pred = (const float*)d_in[0];
    const float* y_true = (const float*)d_in[1];
    float* out = (float*)d_out;

    char* ws = (char*)d_ws;
    float* red = (float*)ws;
    const size_t NB4 = (size_t)NVOX;            // elems in 4 volumes
    float* yp = (float*)(ws + 256);

    const size_t need_batched = 256 + 7 * NB4 * sizeof(float);   // ~235 MB

    hipMemsetAsync(red, 0, 64, stream);
    sigmoid_reduce_kernel<<<SIG_BLOCKS, THREADS, 0, stream>>>(
        (const float4*)y_pred, (const float4*)y_true, (float4*)yp, red);

    if (ws_size >= need_batched) {
        // ---- batched: both skeletons (8 volumes) per dispatch ----
        float* ping = yp + NB4;          // 8-vol
        float* pong = ping + 2 * NB4;    // 8-vol
        float* S    = pong + 2 * NB4;    // 8-vol (pred: vols 0-3, true: 4-7)
        const int zc = 4;                // zlen 32
        dim3 grid(NW / TX, NH / TY, zc * 8);

        skel_step_kernel<0, 0><<<grid, THREADS, 0, stream>>>(
            yp, y_true, nullptr, S, zc, nullptr, nullptr, nullptr, 0);

        float* bufs[2] = {ping, pong};
        for (int i = 0; i < 16; ++i) {
            const float* sA = (i == 0) ? yp : bufs[(i + 1) & 1];
            const float* sB = (i == 0) ? y_true : nullptr;
            float* oimg = bufs[i & 1];
            if (i < 15)
                skel_step_kernel<1, 0><<<grid, THREADS, 0, stream>>>(
                    sA, sB, oimg, S, zc, nullptr, nullptr, nullptr, 0);
            else
                skel_step_kernel<1, 1><<<grid, THREADS, 0, stream>>>(
                    sA, sB, oimg, S, zc, y_true, yp, red, 3);
        }
    } else {
        // ---- sequential fallback: one skeleton stream at a time ----
        float* ping = yp + NB4;
        float* pong = ping + NB4;
        float* Sp   = pong + NB4;
        float* St   = Sp + NB4;
        const int zc = 8;                // zlen 16
        dim3 grid(NW / TX, NH / TY, zc * 4);

        auto run = [&](const float* x, float* S, const float* other, int offBase) {
            skel_step_kernel<0, 0><<<grid, THREADS, 0, stream>>>(
                x, nullptr, nullptr, S, zc, nullptr, nullptr, nullptr, 0);
            float* bufs[2] = {ping, pong};
            for (int i = 0; i < 16; ++i) {
                const float* sA = (i == 0) ? x : bufs[(i + 1) & 1];
                float* oimg = bufs[i & 1];
                if (i < 15)
                    skel_step_kernel<1, 0><<<grid, THREADS, 0, stream>>>(
                        sA, nullptr, oimg, S, zc, nullptr, nullptr, nullptr, 0);
                else
                    skel_step_kernel<1, 1><<<grid, THREADS, 0, stream>>>(
                        sA, nullptr, oimg, S, zc, other, nullptr, red, offBase);
            }
        };
        run(yp, Sp, y_true, 3);
        run(y_true, St, yp, 5);
    }

    finalize_kernel<<<1, 1, 0, stream>>>(red, out);
}

// Round 4
// 1570.570 us; speedup vs baseline: 5.7797x; 1.5988x over previous
//
#include <hip/hip_runtime.h>
#include <cmath>

// Volume: [B=4, C=1, D=128, H=128, W=128] fp32
#define NB 4
#define ND 128
#define NH 128
#define NW 128
#define NVOL_VOX (ND * NH * NW)    // 2097152 per volume
#define NVOX (NB * NVOL_VOX)       // 8388608 (4 volumes)

#define THREADS 256

// z-march tile: 32(x) x 16(y) outputs; x processed as float4.
// All x-extents padded to 40 floats (10 f4), covering gx in [tx0-4, tx0+36).
#define TX 32
#define TY 16
#define QX 10          // f4 columns in padded extent
#define SY 22          // src rows (y halo 3)
#define EY 20          // e1 rows (y halo 2)
#define FY 18          // e2 rows (y halo 1)
#define MY 16          // mxy rows
#define MQ 8           // mxy f4 columns (32 floats)

__device__ __forceinline__ float4 f4min(float4 a, float4 b) {
    return make_float4(fminf(a.x, b.x), fminf(a.y, b.y), fminf(a.z, b.z), fminf(a.w, b.w));
}
__device__ __forceinline__ float4 f4max(float4 a, float4 b) {
    return make_float4(fmaxf(a.x, b.x), fmaxf(a.y, b.y), fmaxf(a.z, b.z), fmaxf(a.w, b.w));
}

// ---------------------------------------------------------------------------
__device__ __forceinline__ float block_reduce(float v, float* sbuf) {
    for (int off = 32; off > 0; off >>= 1) v += __shfl_down(v, off, 64);
    int lane = threadIdx.x & 63;
    int wid  = threadIdx.x >> 6;
    if (lane == 0) sbuf[wid] = v;
    __syncthreads();
    float r = 0.f;
    if (wid == 0) {
        r = (lane < (int)(blockDim.x >> 6)) ? sbuf[lane] : 0.f;
        for (int off = 8; off > 0; off >>= 1) r += __shfl_down(r, off, 64);
    }
    __syncthreads();
    return r;
}

// ---------------------------------------------------------------------------
// sigmoid + dice partial sums (float4, grid-stride)
// ---------------------------------------------------------------------------
#define SIG_BLOCKS 2048
__global__ void sigmoid_reduce_kernel(const float4* __restrict__ logits,
                                      const float4* __restrict__ yt,
                                      float4* __restrict__ yp,
                                      float* __restrict__ red) {
    __shared__ float sbuf[THREADS / 64];
    const int n4 = NVOX / 4;
    float sp = 0.f, st = 0.f, stp = 0.f;
    for (int i = blockIdx.x * blockDim.x + threadIdx.x; i < n4;
         i += gridDim.x * blockDim.x) {
        float4 l = logits[i];
        float4 t = yt[i];
        float4 p;
        p.x = 1.f / (1.f + expf(-l.x));
        p.y = 1.f / (1.f + expf(-l.y));
        p.z = 1.f / (1.f + expf(-l.z));
        p.w = 1.f / (1.f + expf(-l.w));
        yp[i] = p;
        sp  += p.x + p.y + p.z + p.w;
        st  += t.x + t.y + t.z + t.w;
        stp += t.x * p.x + t.y * p.y + t.z * p.z + t.w * p.w;
    }
    float a = block_reduce(sp, sbuf);
    float b = block_reduce(st, sbuf);
    float c = block_reduce(stp, sbuf);
    if (threadIdx.x == 0) {
        atomicAdd(&red[0], a);
        atomicAdd(&red[1], b);
        atomicAdd(&red[2], c);
    }
}

// ---------------------------------------------------------------------------
// Fused z-march skeleton step, float4-vectorized.
// MODE=0 (init): skel = relu(src - dilate(erode(src)))
// MODE=1 (iter): e1 = erode(src); img = e1;
//                delta = relu(e1 - dilate(erode(e1)));
//                skel += relu(delta - skel*delta)
// RED=1: accumulate sum(skel_new), sum(skel_new*other) into red.
// ---------------------------------------------------------------------------
template <int MODE, int RED>
__global__ __launch_bounds__(256, 4)
void skel_step_kernel(const float* __restrict__ srcA, const float* __restrict__ srcB,
                      float* __restrict__ imgOut, float* __restrict__ skel,
                      int zchunks,
                      const float* __restrict__ othA, const float* __restrict__ othB,
                      float* __restrict__ red, int offBase) {
    __shared__ float4 sSrc[4][SY * QX];   // rolling src slices
    __shared__ float4 sE1[3][EY * QX];    // rolling e1 slices
    __shared__ float4 sE2[FY * QX];       // scratch e2 slice (also reduce sbuf)
    __shared__ float4 sMxy[3][MY * MQ];   // rolling xy-max slices

    const float4 INF4  = make_float4(INFINITY, INFINITY, INFINITY, INFINITY);
    const float4 MINF4 = make_float4(-INFINITY, -INFINITY, -INFINITY, -INFINITY);

    const int zlen  = ND / zchunks;
    const int v     = blockIdx.z / zchunks;
    const int chunk = blockIdx.z - v * zchunks;
    const int z0    = chunk * zlen;
    const int tx0   = blockIdx.x * TX;
    const int ty0   = blockIdx.y * TY;
    const int tid   = threadIdx.x;

    const float* src = srcB ? (v < 4 ? srcA + (size_t)v * NVOL_VOX
                                     : srcB + (size_t)(v - 4) * NVOL_VOX)
                            : srcA + (size_t)v * NVOL_VOX;
    const float4* src4 = (const float4*)src;
    float4* img4 = imgOut ? (float4*)(imgOut + (size_t)v * NVOL_VOX) : nullptr;
    float4* skl4 = (float4*)(skel + (size_t)v * NVOL_VOX);
    const float4* oth4 = nullptr;
    int off = offBase;
    if (RED) {
        const float* oth = othB ? (v < 4 ? othA + (size_t)v * NVOL_VOX
                                         : othB + (size_t)(v - 4) * NVOL_VOX)
                                : othA + (size_t)v * NVOL_VOX;
        oth4 = (const float4*)oth;
        if (othB && v >= 4) off = offBase + 2;
    }

    float accS = 0.f, accSO = 0.f;

    // ---- stage: load src slice z (f4; OOB -> +INF) ----
    auto L = [&](int z) {
        float4* dst = sSrc[(z + 512) & 3];
        if (tid < SY * QX) {
            if ((unsigned)z >= ND) {
                dst[tid] = INF4;
            } else {
                int ly = tid / QX, qx = tid - ly * QX;
                int gy = ty0 + ly - 3;
                int gx4 = tx0 + qx * 4 - 4;    // f4 fully in or fully out of [0,NW)
                float4 vv = INF4;
                if ((unsigned)gy < NH && (unsigned)gx4 < NW)
                    vv = src4[(((size_t)z * NH + gy) * NW + gx4) >> 2];
                dst[tid] = vv;
            }
        }
    };

    // ---- stage: e1(z) = 7-pt min erode of src; write img center (MODE1) ----
    auto E1 = [&](int z) {
        float4* dst = sE1[(z + 513) % 3];
        if (tid >= EY * QX) return;
        if ((unsigned)z >= ND) { dst[tid] = INF4; return; }
        const float4* s0 = sSrc[(z - 1 + 512) & 3];
        const float4* s1 = sSrc[(z + 512) & 3];
        const float4* s2 = sSrc[(z + 1 + 512) & 3];
        int ey = tid / QX, qx = tid - ey * QX;
        int c = (ey + 1) * QX + qx;
        float4 cc = s1[c];
        float4 lf = (qx > 0)      ? s1[c - 1] : INF4;
        float4 rt = (qx < QX - 1) ? s1[c + 1] : INF4;
        float4 xm;
        xm.x = fminf(fminf(lf.w, cc.x), cc.y);
        xm.y = fminf(fminf(cc.x, cc.y), cc.z);
        xm.z = fminf(fminf(cc.y, cc.z), cc.w);
        xm.w = fminf(fminf(cc.z, cc.w), rt.x);
        float4 vv = f4min(xm, s1[c - QX]);
        vv = f4min(vv, s1[c + QX]);
        vv = f4min(vv, s0[c]);
        vv = f4min(vv, s2[c]);
        dst[tid] = vv;
        if (MODE == 1 && img4 && z >= z0 && z < z0 + zlen) {
            int cy = ey - 2, q = qx - 1;
            if ((unsigned)cy < TY && (unsigned)q < MQ) {
                int gy = ty0 + cy, gx4 = tx0 + q * 4;
                img4[(((size_t)z * NH + gy) * NW + gx4) >> 2] = vv;
            }
        }
    };

    // ---- stage: mxy(z) = 3x3 xy-max of e2(z) (MODE1: e2=erode(e1); MODE0: e1) ----
    auto MXY = [&](int z) {
        if (MODE == 1) {
            if ((unsigned)z < ND && tid < FY * QX) {
                const float4* e0 = sE1[(z - 1 + 513) % 3];
                const float4* ec = sE1[(z + 513) % 3];
                const float4* e2 = sE1[(z + 1 + 513) % 3];
                int fy = tid / QX, qx = tid - fy * QX;
                int c = (fy + 1) * QX + qx;
                float4 cc = ec[c];
                float4 lf = (qx > 0)      ? ec[c - 1] : INF4;
                float4 rt = (qx < QX - 1) ? ec[c + 1] : INF4;
                float4 xm;
                xm.x = fminf(fminf(lf.w, cc.x), cc.y);
                xm.y = fminf(fminf(cc.x, cc.y), cc.z);
                xm.z = fminf(fminf(cc.y, cc.z), cc.w);
                xm.w = fminf(fminf(cc.z, cc.w), rt.x);
                float4 vv = f4min(xm, ec[c - QX]);
                vv = f4min(vv, ec[c + QX]);
                vv = f4min(vv, e0[c]);
                vv = f4min(vv, e2[c]);
                sE2[tid] = vv;
            }
            __syncthreads();
        }
        float4* dst = sMxy[(z + 513) % 3];
        if (tid < MY * MQ) {
            if ((unsigned)z >= ND) {
                dst[tid] = MINF4;
            } else {
                int my = tid / MQ, qx = tid - my * MQ;
                int sqx = qx + 1;
                float4 vl, vc, vr;
                if (MODE == 1) {
                    int r0 = my * QX, r1 = (my + 1) * QX, r2 = (my + 2) * QX;
                    vl = f4max(f4max(sE2[r0 + sqx - 1], sE2[r1 + sqx - 1]), sE2[r2 + sqx - 1]);
                    vc = f4max(f4max(sE2[r0 + sqx],     sE2[r1 + sqx]),     sE2[r2 + sqx]);
                    vr = f4max(f4max(sE2[r0 + sqx + 1], sE2[r1 + sqx + 1]), sE2[r2 + sqx + 1]);
                } else {
                    const float4* ec = sE1[(z + 513) % 3];
                    int r0 = (my + 1) * QX, r1 = (my + 2) * QX, r2 = (my + 3) * QX;
                    vl = f4max(f4max(ec[r0 + sqx - 1], ec[r1 + sqx - 1]), ec[r2 + sqx - 1]);
                    vc = f4max(f4max(ec[r0 + sqx],     ec[r1 + sqx]),     ec[r2 + sqx]);
                    vr = f4max(f4max(ec[r0 + sqx + 1], ec[r1 + sqx + 1]), ec[r2 + sqx + 1]);
                }
                float4 o;
                o.x = fmaxf(fmaxf(vl.w, vc.x), vc.y);
                o.y = fmaxf(fmaxf(vc.x, vc.y), vc.z);
                o.z = fmaxf(fmaxf(vc.y, vc.z), vc.w);
                o.w = fmaxf(fmaxf(vc.z, vc.w), vr.x);
                dst[tid] = o;
            }
        }
    };

    // ---- stage: output slice z ----
    auto OUT = [&](int z) {
        if (tid >= MY * MQ) return;
        const float4* m0 = sMxy[(z - 1 + 513) % 3];
        const float4* m1 = sMxy[(z + 513) % 3];
        const float4* m2 = sMxy[(z + 1 + 513) % 3];
        int my = tid / MQ, qx = tid - my * MQ;
        float4 dil = f4max(f4max(m0[tid], m1[tid]), m2[tid]);
        float4 ref;
        if (MODE == 1) ref = sE1[(z + 513) % 3][(my + 2) * QX + qx + 1];
        else           ref = sSrc[(z + 512) & 3][(my + 3) * QX + qx + 1];
        int gy = ty0 + my, gx4 = tx0 + qx * 4;
        size_t gi = (((size_t)z * NH + gy) * NW + gx4) >> 2;
        float4 delta;
        delta.x = fmaxf(ref.x - dil.x, 0.f);
        delta.y = fmaxf(ref.y - dil.y, 0.f);
        delta.z = fmaxf(ref.z - dil.z, 0.f);
        delta.w = fmaxf(ref.w - dil.w, 0.f);
        float4 snew;
        if (MODE == 1) {
            float4 s = skl4[gi];
            snew.x = s.x + fmaxf(delta.x - s.x * delta.x, 0.f);
            snew.y = s.y + fmaxf(delta.y - s.y * delta.y, 0.f);
            snew.z = s.z + fmaxf(delta.z - s.z * delta.z, 0.f);
            snew.w = s.w + fmaxf(delta.w - s.w * delta.w, 0.f);
        } else {
            snew = delta;
        }
        skl4[gi] = snew;
        if (RED) {
            accS += snew.x + snew.y + snew.z + snew.w;
            float4 o = oth4[gi];
            accSO += snew.x * o.x + snew.y * o.y + snew.z * o.z + snew.w * o.w;
        }
    };

    // ---- prologue ----
    L(z0 - 3); L(z0 - 2); L(z0 - 1); __syncthreads();
    E1(z0 - 2); __syncthreads();
    L(z0);      __syncthreads();
    E1(z0 - 1); __syncthreads();
    L(z0 + 1);  __syncthreads();
    E1(z0);     __syncthreads();
    MXY(z0 - 1); __syncthreads();
    L(z0 + 2);  __syncthreads();
    E1(z0 + 1); __syncthreads();
    MXY(z0);    __syncthreads();

    // ---- steady state ----
    for (int z = z0; z < z0 + zlen; ++z) {
        L(z + 3);   __syncthreads();
        E1(z + 2);  __syncthreads();
        MXY(z + 1); __syncthreads();
        OUT(z);     __syncthreads();
    }

    if (RED) {
        float* sbuf = (float*)sE2;
        float r1 = block_reduce(accS, sbuf);
        float r2 = block_reduce(accSO, sbuf);
        if (tid == 0) {
            atomicAdd(&red[off], r1);
            atomicAdd(&red[off + 1], r2);
        }
    }
}

// ---------------------------------------------------------------------------
__global__ void finalize_kernel(const float* __restrict__ red, float* __restrict__ out) {
    const float smooth = 1.0f;
    const float alpha = 0.3f;
    float dice = 1.f - (2.f * red[2] + smooth) / (red[1] + red[0] + smooth);
    float tprec = (red[4] + smooth) / (red[3] + smooth);
    float tsens = (red[6] + smooth) / (red[5] + smooth);
    float cl = 1.f - 2.f * (tprec * tsens) / (tprec + tsens);
    out[0] = (1.f - alpha) * dice + alpha * cl;
}

// ---------------------------------------------------------------------------
extern "C" void kernel_launch(void* const* d_in, const int* in_sizes, int n_in,
                              void* d_out, int out_size, void* d_ws, size_t ws_size,
                              hipStream_t stream) {
    const float* y_pred = (const float*)d_in[0];
    const float* y_true = (const float*)d_in[1];
    float* out = (float*)d_out;

    char* ws = (char*)d_ws;
    float* red = (float*)ws;
    const size_t NB4 = (size_t)NVOX;
    float* yp = (float*)(ws + 256);

    const size_t need_batched = 256 + 7 * NB4 * sizeof(float);   // ~235 MB

    hipMemsetAsync(red, 0, 64, stream);
    sigmoid_reduce_kernel<<<SIG_BLOCKS, THREADS, 0, stream>>>(
        (const float4*)y_pred, (const float4*)y_true, (float4*)yp, red);

    if (ws_size >= need_batched) {
        // ---- batched: both skeletons (8 volumes) per dispatch ----
        float* ping = yp + NB4;          // 8-vol
        float* pong = ping + 2 * NB4;    // 8-vol
        float* S    = pong + 2 * NB4;    // 8-vol
        const int zc = 4;                // zlen 32
        dim3 grid(NW / TX, NH / TY, zc * 8);

        skel_step_kernel<0, 0><<<grid, THREADS, 0, stream>>>(
            yp, y_true, nullptr, S, zc, nullptr, nullptr, nullptr, 0);

        float* bufs[2] = {ping, pong};
        for (int i = 0; i < 16; ++i) {
            const float* sA = (i == 0) ? yp : bufs[(i + 1) & 1];
            const float* sB = (i == 0) ? y_true : nullptr;
            float* oimg = (i < 15) ? bufs[i & 1] : nullptr;   // last iter: img dead
            if (i < 15)
                skel_step_kernel<1, 0><<<grid, THREADS, 0, stream>>>(
                    sA, sB, oimg, S, zc, nullptr, nullptr, nullptr, 0);
            else
                skel_step_kernel<1, 1><<<grid, THREADS, 0, stream>>>(
                    sA, sB, oimg, S, zc, y_true, yp, red, 3);
        }
    } else {
        // ---- sequential fallback ----
        float* ping = yp + NB4;
        float* pong = ping + NB4;
        float* Sp   = pong + NB4;
        float* St   = Sp + NB4;
        const int zc = 8;                // zlen 16
        dim3 grid(NW / TX, NH / TY, zc * 4);

        auto run = [&](const float* x, float* S, const float* other, int offBase) {
            skel_step_kernel<0, 0><<<grid, THREADS, 0, stream>>>(
                x, nullptr, nullptr, S, zc, nullptr, nullptr, nullptr, 0);
            float* bufs[2] = {ping, pong};
            for (int i = 0; i < 16; ++i) {
                const float* sA = (i == 0) ? x : bufs[(i + 1) & 1];
                float* oimg = (i < 15) ? bufs[i & 1] : nullptr;
                if (i < 15)
                    skel_step_kernel<1, 0><<<grid, THREADS, 0, stream>>>(
                        sA, nullptr, oimg, S, zc, nullptr, nullptr, nullptr, 0);
                else
                    skel_step_kernel<1, 1><<<grid, THREADS, 0, stream>>>(
                        sA, nullptr, oimg, S, zc, other, nullptr, red, offBase);
            }
        };
        run(yp, Sp, y_true, 3);
        run(y_true, St, yp, 5);
    }

    finalize_kernel<<<1, 1, 0, stream>>>(red, out);
}

// Round 5
// 1386.233 us; speedup vs baseline: 6.5482x; 1.1330x over previous
//
#include <hip/hip_runtime.h>
#include <cmath>

// Volume: [B=4, C=1, D=128, H=128, W=128] fp32
#define NB 4
#define ND 128
#define NH 128
#define NW 128
#define NVOL_VOX (ND * NH * NW)    // 2097152 per volume
#define NVOX (NB * NVOL_VOX)       // 8388608 (4 volumes)

#define THREADS 256

// Register-column z-march tile: 32(x) x 16(y) outputs, f4 columns.
// Frame: 22 rows (y halo 3) x 10 data f4 cols (x halo 1 f4), stride 13 with
// INF guard cols at 0, 11, 12 (data at cols 1..10).
#define TX 32
#define TY 16
#define SSTR 13
#define RSTR 9

__device__ __forceinline__ float4 f4min(float4 a, float4 b) {
    return make_float4(fminf(a.x, b.x), fminf(a.y, b.y), fminf(a.z, b.z), fminf(a.w, b.w));
}
__device__ __forceinline__ float4 f4max(float4 a, float4 b) {
    return make_float4(fmaxf(a.x, b.x), fmaxf(a.y, b.y), fmaxf(a.z, b.z), fmaxf(a.w, b.w));
}

// ---------------------------------------------------------------------------
__device__ __forceinline__ float block_reduce(float v, float* sbuf) {
    for (int off = 32; off > 0; off >>= 1) v += __shfl_down(v, off, 64);
    int lane = threadIdx.x & 63;
    int wid  = threadIdx.x >> 6;
    if (lane == 0) sbuf[wid] = v;
    __syncthreads();
    float r = 0.f;
    if (wid == 0) {
        r = (lane < (int)(blockDim.x >> 6)) ? sbuf[lane] : 0.f;
        for (int off = 8; off > 0; off >>= 1) r += __shfl_down(r, off, 64);
    }
    __syncthreads();
    return r;
}

// ---------------------------------------------------------------------------
// sigmoid + dice partial sums (float4, grid-stride)
// ---------------------------------------------------------------------------
#define SIG_BLOCKS 2048
__global__ void sigmoid_reduce_kernel(const float4* __restrict__ logits,
                                      const float4* __restrict__ yt,
                                      float4* __restrict__ yp,
                                      float* __restrict__ red) {
    __shared__ float sbuf[THREADS / 64];
    const int n4 = NVOX / 4;
    float sp = 0.f, st = 0.f, stp = 0.f;
    for (int i = blockIdx.x * blockDim.x + threadIdx.x; i < n4;
         i += gridDim.x * blockDim.x) {
        float4 l = logits[i];
        float4 t = yt[i];
        float4 p;
        p.x = 1.f / (1.f + expf(-l.x));
        p.y = 1.f / (1.f + expf(-l.y));
        p.z = 1.f / (1.f + expf(-l.z));
        p.w = 1.f / (1.f + expf(-l.w));
        yp[i] = p;
        sp  += p.x + p.y + p.z + p.w;
        st  += t.x + t.y + t.z + t.w;
        stp += t.x * p.x + t.y * p.y + t.z * p.z + t.w * p.w;
    }
    float a = block_reduce(sp, sbuf);
    float b = block_reduce(st, sbuf);
    float c = block_reduce(stp, sbuf);
    if (threadIdx.x == 0) {
        atomicAdd(&red[0], a);
        atomicAdd(&red[1], b);
        atomicAdd(&red[2], c);
    }
}

// ---------------------------------------------------------------------------
// Register-column fused skeleton step.
// MODE=0 (init): skel = relu(src - dilate(erode(src)))
// MODE=1 (iter): e1 = erode(src); img = e1;
//                delta = relu(e1 - dilate(erode(e1)));
//                skel += relu(delta - skel*delta)
// Pipeline lags (zL = z0-3+s): L:zL, e1:zL-1, [e2:zL-2], rx, mxy, OUT.
// One __syncthreads per z-step: every stage reads the slice slot written the
// PREVIOUS step (slot parity s&1) and its own registers only.
// ---------------------------------------------------------------------------
template <int MODE, int RED>
__global__ __launch_bounds__(256, 4)
void skel_step_kernel(const float* __restrict__ srcA, const float* __restrict__ srcB,
                      float* __restrict__ imgOut, float* __restrict__ skel,
                      int zchunks,
                      const float* __restrict__ othA, const float* __restrict__ othB,
                      float* __restrict__ red, int offBase) {
    __shared__ float4 srcS[2][22 * SSTR];
    __shared__ float4 e1S [2][20 * SSTR];
    __shared__ float4 e2S [2][18 * SSTR];
    __shared__ float4 rxS [2][18 * RSTR];

    const float4 INF4  = make_float4(INFINITY, INFINITY, INFINITY, INFINITY);
    const float4 MINF4 = make_float4(-INFINITY, -INFINITY, -INFINITY, -INFINITY);

    const int zlen  = ND / zchunks;
    const int v     = blockIdx.z / zchunks;
    const int chunk = blockIdx.z - v * zchunks;
    const int z0    = chunk * zlen;
    const int tx0   = blockIdx.x * TX;
    const int ty0   = blockIdx.y * TY;
    const int tid   = threadIdx.x;

    const float* src = srcB ? (v < 4 ? srcA + (size_t)v * NVOL_VOX
                                     : srcB + (size_t)(v - 4) * NVOL_VOX)
                            : srcA + (size_t)v * NVOL_VOX;
    const float4* src4 = (const float4*)src;
    float4* img4 = imgOut ? (float4*)(imgOut + (size_t)v * NVOL_VOX) : nullptr;
    float4* skl4 = (float4*)(skel + (size_t)v * NVOL_VOX);
    const float4* oth4 = nullptr;
    int off = offBase;
    if (RED) {
        const float* oth = othB ? (v < 4 ? othA + (size_t)v * NVOL_VOX
                                         : othB + (size_t)(v - 4) * NVOL_VOX)
                                : othA + (size_t)v * NVOL_VOX;
        oth4 = (const float4*)oth;
        if (othB && v >= 4) off = offBase + 2;
    }

    // ---- thread -> column mapping ----
    const int fy = tid / 10, qx = tid - fy * 10;           // fy 0..21 (tid<220)
    const bool tOK = tid < 220;
    const bool aE1 = tOK && fy >= 1 && fy < 21;
    const bool aE2 = tOK && fy >= 2 && fy < 20;
    const bool aRx = aE2 && qx >= 1 && qx < 9;
    const bool aC  = tOK && fy >= 3 && fy < 19 && qx >= 1 && qx < 9;
    const int gy = ty0 + fy - 3;
    const int gx = tx0 + (qx - 1) * 4;
    const bool gOK = tOK && (unsigned)gy < NH && (unsigned)gx < NW;
    const int colBase = gOK ? ((gy * NW + gx) >> 2) : 0;
    const int zS4 = (NH * NW) >> 2;                        // 4096 f4 per z-slice
    const int iSrc = fy * SSTR + qx + 1;
    const int iE1  = (fy - 1) * SSTR + qx + 1;
    const int iE2  = (fy - 2) * SSTR + qx + 1;
    const int iRx  = (fy - 2) * RSTR + (qx - 1);

    // ---- fill guard columns (cols 0,11,12) with +INF, both slots ----
    for (int l = tid; l < 2 * 22 * 3; l += THREADS) {
        int sl = l / 66, r = (l % 66) / 3, c = l % 3;
        srcS[sl][r * SSTR + (c == 0 ? 0 : (c == 1 ? 11 : 12))] = INF4;
    }
    for (int l = tid; l < 2 * 20 * 3; l += THREADS) {
        int sl = l / 60, r = (l % 60) / 3, c = l % 3;
        e1S[sl][r * SSTR + (c == 0 ? 0 : (c == 1 ? 11 : 12))] = INF4;
    }
    for (int l = tid; l < 2 * 18 * 3; l += THREADS) {
        int sl = l / 54, r = (l % 54) / 3, c = l % 3;
        e2S[sl][r * SSTR + (c == 0 ? 0 : (c == 1 ? 11 : 12))] = INF4;
    }
    __syncthreads();

    // ---- register FIFOs ----
    constexpr int SD = (MODE == 1) ? 3 : 6;   // src history depth
    float4 srcF[SD], e1F[6], e2F[2], rxF[2], mxyF[3];
#pragma unroll
    for (int i = 0; i < SD; ++i) srcF[i] = INF4;
#pragma unroll
    for (int i = 0; i < 6; ++i) e1F[i] = INF4;
    e2F[0] = e2F[1] = INF4;
    rxF[0] = rxF[1] = INF4;
    mxyF[0] = mxyF[1] = mxyF[2] = MINF4;

    float accS = 0.f, accSO = 0.f;
    const int NSTEP = zlen + 8;

    for (int sb = 0; sb < NSTEP; sb += 6) {
#pragma unroll
        for (int u = 0; u < 6; ++u) {
            const int s  = sb + u;
            const int zL = z0 - 3 + s;
            const int sl  = u & 1;        // slot written this step (s&1, 6 even)
            const int slp = sl ^ 1;       // slot written last step

            // ---- L: load src(zL) ----
            {
                float4 vv = INF4;
                if ((unsigned)zL < ND && zL < z0 + zlen + 3 && gOK)
                    vv = src4[zL * zS4 + colBase];
                srcF[u % SD] = vv;
                if (tOK) srcS[sl][iSrc] = vv;
            }

            // ---- e1(zL-1) = 7-pt min erode of src ----
            {
                const int z = zL - 1;
                float4 vv = INF4;
                if (aE1 && (unsigned)z < ND) {
                    const float4* S = srcS[slp];
                    float4 cc = srcF[(u + SD - 1) % SD];
                    float4 lf = S[iSrc - 1], rt = S[iSrc + 1];
                    float4 up = S[iSrc - SSTR], dn = S[iSrc + SSTR];
                    float4 xm;
                    xm.x = fminf(fminf(lf.w, cc.x), cc.y);
                    xm.y = fminf(fminf(cc.x, cc.y), cc.z);
                    xm.z = fminf(fminf(cc.y, cc.z), cc.w);
                    xm.w = fminf(fminf(cc.z, cc.w), rt.x);
                    vv = f4min(f4min(xm, up),
                               f4min(dn, f4min(srcF[(u + SD - 2) % SD], srcF[u % SD])));
                    if (MODE == 1 && img4 && aC && z >= z0 && z < z0 + zlen)
                        img4[z * zS4 + colBase] = vv;
                }
                e1F[u] = vv;
                if (aE1) e1S[sl][iE1] = vv;
            }

            // ---- e2(zL-2) = erode(e1)  (MODE1 only) ----
            if (MODE == 1) {
                float4 vv = INF4;
                if (aE2) {
                    const float4* S = e1S[slp];
                    float4 cc = e1F[(u + 5) % 6];
                    float4 lf = S[iE1 - 1], rt = S[iE1 + 1];
                    float4 up = S[iE1 - SSTR], dn = S[iE1 + SSTR];
                    float4 xm;
                    xm.x = fminf(fminf(lf.w, cc.x), cc.y);
                    xm.y = fminf(fminf(cc.x, cc.y), cc.z);
                    xm.z = fminf(fminf(cc.y, cc.z), cc.w);
                    xm.w = fminf(fminf(cc.z, cc.w), rt.x);
                    vv = f4min(f4min(xm, up),
                               f4min(dn, f4min(e1F[(u + 4) % 6], e1F[u])));
                    e2S[sl][iE2] = vv;
                }
                e2F[u % 2] = vv;
            }

            // ---- rx = max3x of (MODE1: e2(zL-3), MODE0: e1(zL-2)) ----
            {
                float4 rxv = MINF4;
                if (aRx) {
                    float4 own; const float4* S; int ii;
                    if (MODE == 1) { own = e2F[(u + 1) % 2]; S = e2S[slp]; ii = iE2; }
                    else           { own = e1F[(u + 5) % 6]; S = e1S[slp]; ii = iE1; }
                    float4 lf = S[ii - 1], rt = S[ii + 1];
                    rxv.x = fmaxf(fmaxf(lf.w, own.x), own.y);
                    rxv.y = fmaxf(fmaxf(own.x, own.y), own.z);
                    rxv.z = fmaxf(fmaxf(own.y, own.z), own.w);
                    rxv.w = fmaxf(fmaxf(own.z, own.w), rt.x);
                    rxS[sl][iRx] = rxv;
                }
                rxF[u % 2] = rxv;
            }

            // ---- mxy = max3y of rx  (z = MODE1 ? zL-4 : zL-3) ----
            {
                const int z = (MODE == 1) ? zL - 4 : zL - 3;
                float4 m = MINF4;
                if (aC && (unsigned)z < ND) {
                    const float4* S = rxS[slp];
                    m = f4max(f4max(rxF[(u + 1) % 2], S[iRx - RSTR]), S[iRx + RSTR]);
                }
                mxyF[u % 3] = m;
            }

            // ---- OUT (z = MODE1 ? zL-5 : zL-4) ----
            {
                const int z = (MODE == 1) ? zL - 5 : zL - 4;
                if (aC && z >= z0 && z < z0 + zlen) {
                    float4 dil = f4max(f4max(mxyF[0], mxyF[1]), mxyF[2]);
                    float4 ref = (MODE == 1) ? e1F[(u + 2) % 6] : srcF[(u + 2) % SD];
                    int gi = z * zS4 + colBase;
                    float4 delta;
                    delta.x = fmaxf(ref.x - dil.x, 0.f);
                    delta.y = fmaxf(ref.y - dil.y, 0.f);
                    delta.z = fmaxf(ref.z - dil.z, 0.f);
                    delta.w = fmaxf(ref.w - dil.w, 0.f);
                    float4 snew;
                    if (MODE == 1) {
                        float4 sv = skl4[gi];
                        snew.x = sv.x + fmaxf(delta.x - sv.x * delta.x, 0.f);
                        snew.y = sv.y + fmaxf(delta.y - sv.y * delta.y, 0.f);
                        snew.z = sv.z + fmaxf(delta.z - sv.z * delta.z, 0.f);
                        snew.w = sv.w + fmaxf(delta.w - sv.w * delta.w, 0.f);
                    } else {
                        snew = delta;
                    }
                    skl4[gi] = snew;
                    if (RED) {
                        accS += snew.x + snew.y + snew.z + snew.w;
                        float4 o = oth4[gi];
                        accSO += snew.x * o.x + snew.y * o.y + snew.z * o.z + snew.w * o.w;
                    }
                }
            }

            __syncthreads();
        }
    }

    if (RED) {
        float* sbuf = (float*)srcS;
        float r1 = block_reduce(accS, sbuf);
        float r2 = block_reduce(accSO, sbuf);
        if (tid == 0) {
            atomicAdd(&red[off], r1);
            atomicAdd(&red[off + 1], r2);
        }
    }
}

// ---------------------------------------------------------------------------
__global__ void finalize_kernel(const float* __restrict__ red, float* __restrict__ out) {
    const float smooth = 1.0f;
    const float alpha = 0.3f;
    float dice = 1.f - (2.f * red[2] + smooth) / (red[1] + red[0] + smooth);
    float tprec = (red[4] + smooth) / (red[3] + smooth);
    float tsens = (red[6] + smooth) / (red[5] + smooth);
    float cl = 1.f - 2.f * (tprec * tsens) / (tprec + tsens);
    out[0] = (1.f - alpha) * dice + alpha * cl;
}

// ---------------------------------------------------------------------------
extern "C" void kernel_launch(void* const* d_in, const int* in_sizes, int n_in,
                              void* d_out, int out_size, void* d_ws, size_t ws_size,
                              hipStream_t stream) {
    const float* y_pred = (const float*)d_in[0];
    const float* y_true = (const float*)d_in[1];
    float* out = (float*)d_out;

    char* ws = (char*)d_ws;
    float* red = (float*)ws;
    const size_t NB4 = (size_t)NVOX;
    float* yp = (float*)(ws + 256);

    const size_t need_batched = 256 + 7 * NB4 * sizeof(float);   // ~235 MB

    hipMemsetAsync(red, 0, 64, stream);
    sigmoid_reduce_kernel<<<SIG_BLOCKS, THREADS, 0, stream>>>(
        (const float4*)y_pred, (const float4*)y_true, (float4*)yp, red);

    if (ws_size >= need_batched) {
        // ---- batched: both skeletons (8 volumes) per dispatch ----
        float* ping = yp + NB4;          // 8-vol
        float* pong = ping + 2 * NB4;    // 8-vol
        float* S    = pong + 2 * NB4;    // 8-vol
        const int zc = 4;                // zlen 32
        dim3 grid(NW / TX, NH / TY, zc * 8);

        skel_step_kernel<0, 0><<<grid, THREADS, 0, stream>>>(
            yp, y_true, nullptr, S, zc, nullptr, nullptr, nullptr, 0);

        float* bufs[2] = {ping, pong};
        for (int i = 0; i < 16; ++i) {
            const float* sA = (i == 0) ? yp : bufs[(i + 1) & 1];
            const float* sB = (i == 0) ? y_true : nullptr;
            float* oimg = (i < 15) ? bufs[i & 1] : nullptr;   // last iter: img dead
            if (i < 15)
                skel_step_kernel<1, 0><<<grid, THREADS, 0, stream>>>(
                    sA, sB, oimg, S, zc, nullptr, nullptr, nullptr, 0);
            else
                skel_step_kernel<1, 1><<<grid, THREADS, 0, stream>>>(
                    sA, sB, oimg, S, zc, y_true, yp, red, 3);
        }
    } else {
        // ---- sequential fallback ----
        float* ping = yp + NB4;
        float* pong = ping + NB4;
        float* Sp   = pong + NB4;
        float* St   = Sp + NB4;
        const int zc = 8;                // zlen 16
        dim3 grid(NW / TX, NH / TY, zc * 4);

        auto run = [&](const float* x, float* S, const float* other, int offBase) {
            skel_step_kernel<0, 0><<<grid, THREADS, 0, stream>>>(
                x, nullptr, nullptr, S, zc, nullptr, nullptr, nullptr, 0);
            float* bufs[2] = {ping, pong};
            for (int i = 0; i < 16; ++i) {
                const float* sA = (i == 0) ? x : bufs[(i + 1) & 1];
                float* oimg = (i < 15) ? bufs[i & 1] : nullptr;
                if (i < 15)
                    skel_step_kernel<1, 0><<<grid, THREADS, 0, stream>>>(
                        sA, nullptr, oimg, S, zc, nullptr, nullptr, nullptr, 0);
                else
                    skel_step_kernel<1, 1><<<grid, THREADS, 0, stream>>>(
                        sA, nullptr, oimg, S, zc, other, nullptr, red, offBase);
            }
        };
        run(yp, Sp, y_true, 3);
        run(y_true, St, yp, 5);
    }

    finalize_kernel<<<1, 1, 0, stream>>>(red, out);
}

// Round 6
// 1116.067 us; speedup vs baseline: 8.1334x; 1.2421x over previous
//
#include <hip/hip_runtime.h>
#include <cmath>

// Volume: [B=4, C=1, D=128, H=128, W=128] fp32
#define NB 4
#define ND 128
#define NH 128
#define NW 128
#define NVOL_VOX (ND * NH * NW)    // 2097152 per volume
#define NVOX (NB * NVOL_VOX)       // 8388608 (4 volumes)

#define THREADS 256
#define TX 32
#define TY 16
#define SSTR 13
#define RSTR 9
#define ZS4 ((NH * NW) >> 2)       // 4096 f4 per z-slice

__device__ __forceinline__ float4 f4min(float4 a, float4 b) {
    return make_float4(fminf(a.x, b.x), fminf(a.y, b.y), fminf(a.z, b.z), fminf(a.w, b.w));
}
__device__ __forceinline__ float4 f4max(float4 a, float4 b) {
    return make_float4(fmaxf(a.x, b.x), fmaxf(a.y, b.y), fmaxf(a.z, b.z), fmaxf(a.w, b.w));
}
__device__ __forceinline__ float4 f4relu_sub(float4 a, float4 b) {
    return make_float4(fmaxf(a.x - b.x, 0.f), fmaxf(a.y - b.y, 0.f),
                       fmaxf(a.z - b.z, 0.f), fmaxf(a.w - b.w, 0.f));
}
// x-window min/max within f4 stream: out.i = op(prev, cur, next) shifted
__device__ __forceinline__ float4 f4winmin(float4 lf, float4 cc, float4 rt) {
    float4 o;
    o.x = fminf(fminf(lf.w, cc.x), cc.y);
    o.y = fminf(fminf(cc.x, cc.y), cc.z);
    o.z = fminf(fminf(cc.y, cc.z), cc.w);
    o.w = fminf(fminf(cc.z, cc.w), rt.x);
    return o;
}
__device__ __forceinline__ float4 f4winmax(float4 lf, float4 cc, float4 rt) {
    float4 o;
    o.x = fmaxf(fmaxf(lf.w, cc.x), cc.y);
    o.y = fmaxf(fmaxf(cc.x, cc.y), cc.z);
    o.z = fmaxf(fmaxf(cc.y, cc.z), cc.w);
    o.w = fmaxf(fmaxf(cc.z, cc.w), rt.x);
    return o;
}

__device__ __forceinline__ float block_reduce(float v, float* sbuf) {
    for (int off = 32; off > 0; off >>= 1) v += __shfl_down(v, off, 64);
    int lane = threadIdx.x & 63;
    int wid  = threadIdx.x >> 6;
    if (lane == 0) sbuf[wid] = v;
    __syncthreads();
    float r = 0.f;
    if (wid == 0) {
        r = (lane < (int)(blockDim.x >> 6)) ? sbuf[lane] : 0.f;
        for (int off = 8; off > 0; off >>= 1) r += __shfl_down(r, off, 64);
    }
    __syncthreads();
    return r;
}

// ---------------------------------------------------------------------------
// sigmoid + dice partials: part[b]=sum yp, part[1024+b]=sum yt, part[2048+b]=sum yt*yp
// ---------------------------------------------------------------------------
#define SIG_BLOCKS 1024
__global__ void sigmoid_reduce_kernel(const float4* __restrict__ logits,
                                      const float4* __restrict__ yt,
                                      float4* __restrict__ yp,
                                      float* __restrict__ part) {
    __shared__ float sbuf[THREADS / 64];
    const int n4 = NVOX / 4;
    float sp = 0.f, st = 0.f, stp = 0.f;
    for (int i = blockIdx.x * blockDim.x + threadIdx.x; i < n4;
         i += gridDim.x * blockDim.x) {
        float4 l = logits[i];
        float4 t = yt[i];
        float4 p;
        p.x = 1.f / (1.f + expf(-l.x));
        p.y = 1.f / (1.f + expf(-l.y));
        p.z = 1.f / (1.f + expf(-l.z));
        p.w = 1.f / (1.f + expf(-l.w));
        yp[i] = p;
        sp  += p.x + p.y + p.z + p.w;
        st  += t.x + t.y + t.z + t.w;
        stp += t.x * p.x + t.y * p.y + t.z * p.z + t.w * p.w;
    }
    float a = block_reduce(sp, sbuf);
    float b = block_reduce(st, sbuf);
    float c = block_reduce(stp, sbuf);
    if (threadIdx.x == 0) {
        part[blockIdx.x]        = a;
        part[1024 + blockIdx.x] = b;
        part[2048 + blockIdx.x] = c;
    }
}

// ---------------------------------------------------------------------------
// Init step (round-5 structure, MODE 0): skel = relu(src - dilate(erode(src)))
// ---------------------------------------------------------------------------
__global__ __launch_bounds__(256, 4)
void init_step_kernel(const float* __restrict__ srcA, const float* __restrict__ srcB,
                      float* __restrict__ skel, int zchunks) {
    __shared__ float4 srcS[2][22 * SSTR];
    __shared__ float4 e1S [2][20 * SSTR];
    __shared__ float4 rxS [2][18 * RSTR];

    const float4 INF4  = make_float4(INFINITY, INFINITY, INFINITY, INFINITY);
    const float4 MINF4 = make_float4(-INFINITY, -INFINITY, -INFINITY, -INFINITY);

    const int zlen  = ND / zchunks;
    const int v     = blockIdx.z / zchunks;
    const int chunk = blockIdx.z - v * zchunks;
    const int z0    = chunk * zlen;
    const int tx0   = blockIdx.x * TX;
    const int ty0   = blockIdx.y * TY;
    const int tid   = threadIdx.x;

    const float* src = srcB ? (v < 4 ? srcA + (size_t)v * NVOL_VOX
                                     : srcB + (size_t)(v - 4) * NVOL_VOX)
                            : srcA + (size_t)v * NVOL_VOX;
    const float4* src4 = (const float4*)src;
    float4* skl4 = (float4*)(skel + (size_t)v * NVOL_VOX);

    const int fy = tid / 10, qx = tid - (tid / 10) * 10;
    const bool tOK = tid < 220;
    const bool aE1 = tOK && fy >= 1 && fy < 21;
    const bool aRx = tOK && fy >= 2 && fy < 20 && qx >= 1 && qx < 9;
    const bool aC  = tOK && fy >= 3 && fy < 19 && qx >= 1 && qx < 9;
    const int gy = ty0 + fy - 3;
    const int gx4 = tx0 + (qx - 1) * 4;
    const bool gOK = tOK && (unsigned)gy < NH && (unsigned)gx4 < NW;
    const int colBase = gOK ? ((gy * NW + gx4) >> 2) : 0;
    const int iSrc = fy * SSTR + qx + 1;
    const int iE1  = (fy - 1) * SSTR + qx + 1;
    const int iRx  = (fy - 2) * RSTR + (qx - 1);

    for (int l = tid; l < 2 * 22 * 3; l += THREADS) {
        int sl = l / 66, r = (l % 66) / 3, c = l % 3;
        srcS[sl][r * SSTR + (c == 0 ? 0 : (c == 1 ? 11 : 12))] = INF4;
    }
    for (int l = tid; l < 2 * 20 * 3; l += THREADS) {
        int sl = l / 60, r = (l % 60) / 3, c = l % 3;
        e1S[sl][r * SSTR + (c == 0 ? 0 : (c == 1 ? 11 : 12))] = INF4;
    }
    __syncthreads();

    float4 srcF[6], e1F[2], rxF[2], mxyF[3];
#pragma unroll
    for (int i = 0; i < 6; ++i) srcF[i] = INF4;
    e1F[0] = e1F[1] = INF4;
    rxF[0] = rxF[1] = MINF4;
    mxyF[0] = mxyF[1] = mxyF[2] = MINF4;

    const int NSTEP = zlen + 8;
    for (int sb = 0; sb < NSTEP; sb += 6) {
#pragma unroll
        for (int u = 0; u < 6; ++u) {
            const int s  = sb + u;
            const int zL = z0 - 3 + s;
            const int sl  = u & 1;
            const int slp = sl ^ 1;

            {   // L(zL)
                float4 vv = INF4;
                if ((unsigned)zL < ND && zL < z0 + zlen + 3 && gOK)
                    vv = src4[zL * ZS4 + colBase];
                srcF[u % 6] = vv;
                if (tOK) srcS[sl][iSrc] = vv;
            }
            {   // e1(zL-1)
                const int z = zL - 1;
                float4 vv = INF4;
                if (aE1 && (unsigned)z < ND) {
                    const float4* S = srcS[slp];
                    float4 xm = f4winmin(S[iSrc - 1], srcF[(u + 5) % 6], S[iSrc + 1]);
                    vv = f4min(f4min(xm, S[iSrc - SSTR]),
                               f4min(S[iSrc + SSTR],
                                     f4min(srcF[(u + 4) % 6], srcF[u % 6])));
                }
                e1F[u % 2] = vv;
                if (aE1) e1S[sl][iE1] = vv;
            }
            {   // rx(zL-2) = max3x(e1)
                float4 rxv = MINF4;
                if (aRx) {
                    const float4* S = e1S[slp];
                    rxv = f4winmax(S[iE1 - 1], e1F[(u + 1) % 2], S[iE1 + 1]);
                    rxS[sl][iRx] = rxv;
                }
                rxF[u % 2] = rxv;
            }
            {   // mxy(zL-3) = max3y(rx)
                float4 m = MINF4;
                if (aC)
                    m = f4max(f4max(rxF[(u + 1) % 2], rxS[slp][iRx - RSTR]),
                              rxS[slp][iRx + RSTR]);
                mxyF[u % 3] = m;
            }
            {   // OUT(zL-4): skel = relu(src - dil)
                const int z = zL - 4;
                if (aC && z >= z0 && z < z0 + zlen) {
                    float4 dil = f4max(f4max(mxyF[0], mxyF[1]), mxyF[2]);
                    float4 ref = srcF[(u + 2) % 6];
                    skl4[z * ZS4 + colBase] = f4relu_sub(ref, dil);
                }
            }
            __syncthreads();
        }
    }
}

// ---------------------------------------------------------------------------
// Fused PAIR of skeleton iterations (shared erosion chain E1,E2,E3):
//   E1 = erode(src); E2 = erode(E1) [= img out]; E3 = erode(E2)
//   deltaA = relu(E1 - dilate(E2));  deltaB = relu(E2 - dilate(E3))
//   s1 = s + relu(dA - s*dA); s2 = s1 + relu(dB - s1*dB); skel = s2
// Lags (zL = z0-4+s): L:zL, E1:zL-1, E2:zL-2, E3/rxA:zL-3, rxB/mxyA:zL-4,
// mxyB/dA:zL-5, OUT:zL-6.
// ---------------------------------------------------------------------------
template <int RED>
__global__ __launch_bounds__(256, 3)
void skel_pair_kernel(const float* __restrict__ srcA, const float* __restrict__ srcB,
                      float* __restrict__ imgOut, float* __restrict__ skel,
                      int zchunks,
                      const float* __restrict__ othA, const float* __restrict__ othB,
                      float* __restrict__ part, int offBase) {
    __shared__ float4 srcS[2][24 * SSTR];
    __shared__ float4 e1S [2][22 * SSTR];
    __shared__ float4 e2S [2][20 * SSTR];
    __shared__ float4 e3S [2][18 * SSTR];
    __shared__ float4 rxAS[2][18 * RSTR];
    __shared__ float4 rxBS[2][18 * RSTR];

    const float4 INF4  = make_float4(INFINITY, INFINITY, INFINITY, INFINITY);
    const float4 MINF4 = make_float4(-INFINITY, -INFINITY, -INFINITY, -INFINITY);

    const int zlen  = ND / zchunks;
    const int v     = blockIdx.z / zchunks;
    const int chunk = blockIdx.z - v * zchunks;
    const int z0    = chunk * zlen;
    const int tx0   = blockIdx.x * TX;
    const int ty0   = blockIdx.y * TY;
    const int tid   = threadIdx.x;

    const float* src = srcB ? (v < 4 ? srcA + (size_t)v * NVOL_VOX
                                     : srcB + (size_t)(v - 4) * NVOL_VOX)
                            : srcA + (size_t)v * NVOL_VOX;
    const float4* src4 = (const float4*)src;
    float4* img4 = imgOut ? (float4*)(imgOut + (size_t)v * NVOL_VOX) : nullptr;
    float4* skl4 = (float4*)(skel + (size_t)v * NVOL_VOX);
    const float4* oth4 = nullptr;
    if (RED) {
        const float* oth = othB ? (v < 4 ? othA + (size_t)v * NVOL_VOX
                                         : othB + (size_t)(v - 4) * NVOL_VOX)
                                : othA + (size_t)v * NVOL_VOX;
        oth4 = (const float4*)oth;
    }

    const int fy = tid / 10, qx = tid - (tid / 10) * 10;   // rows 0..23
    const bool tOK = tid < 240;
    const bool aE1 = tOK && fy >= 1 && fy < 23;
    const bool aE2 = tOK && fy >= 2 && fy < 22;
    const bool aE3 = tOK && fy >= 3 && fy < 21;
    const bool aRx = aE3 && qx >= 1 && qx < 9;
    const bool aC  = tOK && fy >= 4 && fy < 20 && qx >= 1 && qx < 9;
    const int gy = ty0 + fy - 4;
    const int gx4 = tx0 + (qx - 1) * 4;
    const bool gOK = tOK && (unsigned)gy < NH && (unsigned)gx4 < NW;
    const int colBase = gOK ? ((gy * NW + gx4) >> 2) : 0;
    const int iSrc = fy * SSTR + qx + 1;
    const int iE1  = (fy - 1) * SSTR + qx + 1;
    const int iE2  = (fy - 2) * SSTR + qx + 1;
    const int iE3  = (fy - 3) * SSTR + qx + 1;
    const int iRx  = (fy - 3) * RSTR + (qx - 1);

    // guard columns (0,11,12) = +INF for all min/max frames
    for (int l = tid; l < 2 * 24 * 3; l += THREADS) {
        int sl = l / 72, r = (l % 72) / 3, c = l % 3;
        srcS[sl][r * SSTR + (c == 0 ? 0 : (c == 1 ? 11 : 12))] = INF4;
    }
    for (int l = tid; l < 2 * 22 * 3; l += THREADS) {
        int sl = l / 66, r = (l % 66) / 3, c = l % 3;
        e1S[sl][r * SSTR + (c == 0 ? 0 : (c == 1 ? 11 : 12))] = INF4;
    }
    for (int l = tid; l < 2 * 20 * 3; l += THREADS) {
        int sl = l / 60, r = (l % 60) / 3, c = l % 3;
        e2S[sl][r * SSTR + (c == 0 ? 0 : (c == 1 ? 11 : 12))] = INF4;
    }
    for (int l = tid; l < 2 * 18 * 3; l += THREADS) {
        int sl = l / 54, r = (l % 54) / 3, c = l % 3;
        e3S[sl][r * SSTR + (c == 0 ? 0 : (c == 1 ? 11 : 12))] = INF4;
    }
    __syncthreads();

    float4 srcF[3], e1F[6], e2F[6], e3F[2], rxAF[2], rxBF[2], mxyAF[3], mxyBF[3], dAF[2];
#pragma unroll
    for (int i = 0; i < 3; ++i) srcF[i] = INF4;
#pragma unroll
    for (int i = 0; i < 6; ++i) { e1F[i] = INF4; e2F[i] = INF4; }
    e3F[0] = e3F[1] = INF4;
    rxAF[0] = rxAF[1] = MINF4;
    rxBF[0] = rxBF[1] = MINF4;
    mxyAF[0] = mxyAF[1] = mxyAF[2] = MINF4;
    mxyBF[0] = mxyBF[1] = mxyBF[2] = MINF4;
    dAF[0] = dAF[1] = make_float4(0.f, 0.f, 0.f, 0.f);

    float accS = 0.f, accSO = 0.f;
    const int NSTEP = zlen + 10;

    for (int sb = 0; sb < NSTEP; sb += 6) {
#pragma unroll
        for (int u = 0; u < 6; ++u) {
            const int s  = sb + u;
            const int zL = z0 - 4 + s;
            const int sl  = u & 1;
            const int slp = sl ^ 1;

            {   // L(zL)
                float4 vv = INF4;
                if ((unsigned)zL < ND && zL < z0 + zlen + 4 && gOK)
                    vv = src4[zL * ZS4 + colBase];
                srcF[u % 3] = vv;
                if (tOK) srcS[sl][iSrc] = vv;
            }
            {   // E1(zL-1)
                const int z = zL - 1;
                float4 vv = INF4;
                if (aE1 && (unsigned)z < ND) {
                    const float4* S = srcS[slp];
                    float4 xm = f4winmin(S[iSrc - 1], srcF[(u + 2) % 3], S[iSrc + 1]);
                    vv = f4min(f4min(xm, S[iSrc - SSTR]),
                               f4min(S[iSrc + SSTR],
                                     f4min(srcF[(u + 1) % 3], srcF[u % 3])));
                }
                e1F[u % 6] = vv;
                if (aE1) e1S[sl][iE1] = vv;
            }
            {   // E2(zL-2) — img output
                const int z = zL - 2;
                float4 vv = INF4;
                if (aE2) {
                    const float4* S = e1S[slp];
                    float4 xm = f4winmin(S[iE1 - 1], e1F[(u + 5) % 6], S[iE1 + 1]);
                    vv = f4min(f4min(xm, S[iE1 - SSTR]),
                               f4min(S[iE1 + SSTR],
                                     f4min(e1F[(u + 4) % 6], e1F[u % 6])));
                    e2S[sl][iE2] = vv;
                    if (img4 && aC && z >= z0 && z < z0 + zlen)
                        img4[z * ZS4 + colBase] = vv;
                }
                e2F[u % 6] = vv;
            }
            {   // E3(zL-3)
                float4 vv = INF4;
                if (aE3) {
                    const float4* S = e2S[slp];
                    float4 xm = f4winmin(S[iE2 - 1], e2F[(u + 5) % 6], S[iE2 + 1]);
                    vv = f4min(f4min(xm, S[iE2 - SSTR]),
                               f4min(S[iE2 + SSTR],
                                     f4min(e2F[(u + 4) % 6], e2F[u % 6])));
                    e3S[sl][iE3] = vv;
                }
                e3F[u % 2] = vv;
            }
            {   // rxA(zL-3) = max3x(E2(zL-3))
                float4 rxv = MINF4;
                if (aRx) {
                    const float4* S = e2S[slp];
                    rxv = f4winmax(S[iE2 - 1], e2F[(u + 5) % 6], S[iE2 + 1]);
                    rxAS[sl][iRx] = rxv;
                }
                rxAF[u % 2] = rxv;
            }
            {   // rxB(zL-4) = max3x(E3(zL-4))
                float4 rxv = MINF4;
                if (aRx) {
                    const float4* S = e3S[slp];
                    rxv = f4winmax(S[iE3 - 1], e3F[(u + 1) % 2], S[iE3 + 1]);
                    rxBS[sl][iRx] = rxv;
                }
                rxBF[u % 2] = rxv;
            }
            {   // mxyA(zL-4), mxyB(zL-5)
                float4 mA = MINF4, mB = MINF4;
                if (aC) {
                    mA = f4max(f4max(rxAF[(u + 1) % 2], rxAS[slp][iRx - RSTR]),
                               rxAS[slp][iRx + RSTR]);
                    mB = f4max(f4max(rxBF[(u + 1) % 2], rxBS[slp][iRx - RSTR]),
                               rxBS[slp][iRx + RSTR]);
                }
                mxyAF[u % 3] = mA;
                mxyBF[u % 3] = mB;
            }
            {   // dA(zL-5) = relu(E1(zL-5) - dilA)
                float4 dilA = f4max(f4max(mxyAF[0], mxyAF[1]), mxyAF[2]);
                dAF[u % 2] = f4relu_sub(e1F[(u + 2) % 6], dilA);
            }
            {   // OUT(zL-6): apply dA then dB
                const int z = zL - 6;
                if (aC && z >= z0 && z < z0 + zlen) {
                    float4 dilB = f4max(f4max(mxyBF[0], mxyBF[1]), mxyBF[2]);
                    float4 dB = f4relu_sub(e2F[(u + 2) % 6], dilB);
                    float4 da = dAF[(u + 1) % 2];
                    int gi = z * ZS4 + colBase;
                    float4 sv = skl4[gi];
                    float4 s1, s2;
                    s1.x = sv.x + fmaxf(da.x - sv.x * da.x, 0.f);
                    s1.y = sv.y + fmaxf(da.y - sv.y * da.y, 0.f);
                    s1.z = sv.z + fmaxf(da.z - sv.z * da.z, 0.f);
                    s1.w = sv.w + fmaxf(da.w - sv.w * da.w, 0.f);
                    s2.x = s1.x + fmaxf(dB.x - s1.x * dB.x, 0.f);
                    s2.y = s1.y + fmaxf(dB.y - s1.y * dB.y, 0.f);
                    s2.z = s1.z + fmaxf(dB.z - s1.z * dB.z, 0.f);
                    s2.w = s1.w + fmaxf(dB.w - s1.w * dB.w, 0.f);
                    skl4[gi] = s2;
                    if (RED) {
                        accS += s2.x + s2.y + s2.z + s2.w;
                        float4 o = oth4[gi];
                        accSO += s2.x * o.x + s2.y * o.y + s2.z * o.z + s2.w * o.w;
                    }
                }
            }
            __syncthreads();
        }
    }

    if (RED) {
        float* sbuf = (float*)srcS;
        float r1 = block_reduce(accS, sbuf);
        float r2 = block_reduce(accSO, sbuf);
        if (tid == 0) {
            int halfSel = (othB && v >= 4) ? 1 : 0;
            int A = (offBase + 2 * halfSel) * 1024;
            int zslot = chunk + zchunks * (v & 3);
            int bid = blockIdx.x + 4 * (blockIdx.y + 8 * zslot);
            part[A + bid] = r1;
            part[A + 1024 + bid] = r2;
        }
    }
}

// ---------------------------------------------------------------------------
// finalize: sum 7 partial arrays (1024 each) and compute the loss scalar
// part arrays: 0 sum_yp, 1 sum_yt, 2 sum_yt_yp, 3 sum_skP, 4 sum_skP_yt,
//              5 sum_skT, 6 sum_skT_yp
// ---------------------------------------------------------------------------
__global__ void finalize_kernel(const float* __restrict__ part, float* __restrict__ out) {
    __shared__ float sbuf[THREADS / 64];
    float s[7];
#pragma unroll
    for (int k = 0; k < 7; ++k) {
        float local = 0.f;
        for (int i = threadIdx.x; i < 1024; i += THREADS) local += part[k * 1024 + i];
        s[k] = block_reduce(local, sbuf);
    }
    if (threadIdx.x == 0) {
        const float smooth = 1.0f;
        const float alpha = 0.3f;
        float dice = 1.f - (2.f * s[2] + smooth) / (s[1] + s[0] + smooth);
        float tprec = (s[4] + smooth) / (s[3] + smooth);
        float tsens = (s[6] + smooth) / (s[5] + smooth);
        float cl = 1.f - 2.f * (tprec * tsens) / (tprec + tsens);
        out[0] = (1.f - alpha) * dice + alpha * cl;
    }
}

// ---------------------------------------------------------------------------
extern "C" void kernel_launch(void* const* d_in, const int* in_sizes, int n_in,
                              void* d_out, int out_size, void* d_ws, size_t ws_size,
                              hipStream_t stream) {
    const float* y_pred = (const float*)d_in[0];
    const float* y_true = (const float*)d_in[1];
    float* out = (float*)d_out;

    char* ws = (char*)d_ws;
    float* part = (float*)ws;                 // 7 * 1024 floats
    float* yp = (float*)(ws + 32768);
    const size_t NB4 = (size_t)NVOX;
    const size_t need_batched = 32768 + 7 * NB4 * sizeof(float);

    hipMemsetAsync(part, 0, 7 * 1024 * sizeof(float), stream);
    sigmoid_reduce_kernel<<<SIG_BLOCKS, THREADS, 0, stream>>>(
        (const float4*)y_pred, (const float4*)y_true, (float4*)yp, part);

    if (ws_size >= need_batched) {
        // batched: both skeletons (8 volumes) per dispatch
        float* ping = yp + NB4;          // 8-vol
        float* pong = ping + 2 * NB4;    // 8-vol
        float* S    = pong + 2 * NB4;    // 8-vol
        const int zc = 4;                // zlen 32
        dim3 grid(NW / TX, NH / TY, zc * 8);

        init_step_kernel<<<grid, THREADS, 0, stream>>>(yp, y_true, S, zc);

        float* bufs[2] = {ping, pong};
        for (int i = 0; i < 8; ++i) {
            const float* sA = (i == 0) ? yp : bufs[(i + 1) & 1];
            const float* sB = (i == 0) ? y_true : nullptr;
            float* oimg = (i < 7) ? bufs[i & 1] : nullptr;   // last pair: img dead
            if (i < 7)
                skel_pair_kernel<0><<<grid, THREADS, 0, stream>>>(
                    sA, sB, oimg, S, zc, nullptr, nullptr, nullptr, 0);
            else
                skel_pair_kernel<1><<<grid, THREADS, 0, stream>>>(
                    sA, sB, oimg, S, zc, y_true, yp, part, 3);
        }
    } else {
        // sequential fallback: one skeleton stream (4 vols) at a time
        float* ping = yp + NB4;
        float* pong = ping + NB4;
        float* Sp   = pong + NB4;
        float* St   = Sp + NB4;
        const int zc = 8;                // zlen 16
        dim3 grid(NW / TX, NH / TY, zc * 4);

        auto run = [&](const float* x, float* S, const float* other, int offBase) {
            init_step_kernel<<<grid, THREADS, 0, stream>>>(x, nullptr, S, zc);
            float* bufs[2] = {ping, pong};
            for (int i = 0; i < 8; ++i) {
                const float* sA = (i == 0) ? x : bufs[(i + 1) & 1];
                float* oimg = (i < 7) ? bufs[i & 1] : nullptr;
                if (i < 7)
                    skel_pair_kernel<0><<<grid, THREADS, 0, stream>>>(
                        sA, nullptr, oimg, S, zc, nullptr, nullptr, nullptr, 0);
                else
                    skel_pair_kernel<1><<<grid, THREADS, 0, stream>>>(
                        sA, nullptr, oimg, S, zc, other, nullptr, part, offBase);
            }
        };
        run(yp, Sp, y_true, 3);
        run(y_true, St, yp, 5);
    }

    finalize_kernel<<<1, THREADS, 0, stream>>>(part, out);
}